// Round 11
// baseline (129.727 us; speedup 1.0000x reference)
//
#include <hip/hip_runtime.h>
#include <hip/hip_bf16.h>

typedef unsigned short u16;
typedef unsigned int u32;
typedef __attribute__((ext_vector_type(8))) short short8;
typedef __attribute__((ext_vector_type(4))) float floatx4;

#define BATCH 16
#define CDIM 512
#define NSPAT 1024
#define NGROUP 8

__device__ __forceinline__ u16 f2bf(float f) {
    unsigned u = __float_as_uint(f);
    u += 0x7FFFu + ((u >> 16) & 1u);   // RNE
    return (u16)(u >> 16);
}
__device__ __forceinline__ u32 f2bf2(float lo, float hi) {   // packed v_cvt_pk_bf16_f32
    __hip_bfloat162 h = __float22bfloat162_rn(make_float2(lo, hi));
    return *(u32*)&h;
}
__device__ __forceinline__ float bf2f(u16 v) {
    u32 t = ((u32)v) << 16;
    return __uint_as_float(t);
}

__device__ __forceinline__ void load_lds16(const void* g, void* l) {
    __builtin_amdgcn_global_load_lds(
        (const __attribute__((address_space(1))) unsigned int*)g,
        (__attribute__((address_space(3))) unsigned int*)l, 16, 0, 0);
}

#define SBAR0 __builtin_amdgcn_sched_barrier(0)
#define BARRIER { SBAR0; __builtin_amdgcn_s_barrier(); SBAR0; }

// ================= D1 prep =================
// blocks [0,256):    w_proj cvt -> wproj_bf
//        [256,448):  transpose wq/wk/wv -> wq_t/wk_t/wv_t (64x64 tiles)
//        [448,960):  GroupNorm partial sums (4 spatial chunks per (batch,group))
//        [960,992):  zero lsums+rbuf (contiguous 128KB)
//        [992,1000): bpv[o] = sum_c w_proj[o][c] * b_qkv[1024+c]
//        [1000,1002): cvec[b] = sum_m w_qkv[512+m][b] * b_qkv[m]   (c = Wk^T bq)
__global__ __launch_bounds__(256) void prep_kernel(
    const float* __restrict__ w_qkv, const float* __restrict__ w_proj,
    const float* __restrict__ b_qkv, const float* __restrict__ x,
    u16* __restrict__ wproj_bf, u16* __restrict__ wq_t, u16* __restrict__ wk_t,
    u16* __restrict__ wv_t, float* __restrict__ stats_part, float* __restrict__ lsums,
    float* __restrict__ bpv, float* __restrict__ cvec) {
    int b = blockIdx.x;
    int tid = threadIdx.x;
    if (b < 256) {  // w_proj -> bf16
        int i = b * 256 + tid;
        float4 v = ((const float4*)w_proj)[i];
        u32* d = (u32*)wproj_bf;
        d[i * 2] = f2bf2(v.x, v.y);
        d[i * 2 + 1] = f2bf2(v.z, v.w);
        return;
    }
    if (b < 448) {  // transpose w_qkv section -> *_t[ci][m], 64x64 tiles
        __shared__ u16 t[64 * 66];
        int bt = b - 256;
        int which = bt >> 6;            // 0=wq, 1=wk, 2=wv
        int bt2 = bt & 63;
        int tx = bt2 & 7, ty = bt2 >> 3;
        const float* src = w_qkv + (size_t)(which * 512 + ty * 64) * CDIM + tx * 64;
        u16* dstb = (which == 0) ? wq_t : (which == 1) ? wk_t : wv_t;
#pragma unroll
        for (int p = 0; p < 4; ++p) {
            int r = p * 16 + (tid >> 4);
            int c4 = (tid & 15) << 2;
            float4 v = *(const float4*)(src + (size_t)r * CDIM + c4);
            u16* d = &t[r * 66 + c4];
            d[0] = f2bf(v.x); d[1] = f2bf(v.y); d[2] = f2bf(v.z); d[3] = f2bf(v.w);
        }
        __syncthreads();
        u16* dst = dstb + (size_t)(tx * 64) * CDIM + ty * 64;
#pragma unroll
        for (int p = 0; p < 4; ++p) {
            int c = p * 16 + (tid >> 4);
            int r4 = (tid & 15) << 2;
            ushort4 o;
            o.x = t[(r4 + 0) * 66 + c];
            o.y = t[(r4 + 1) * 66 + c];
            o.z = t[(r4 + 2) * 66 + c];
            o.w = t[(r4 + 3) * 66 + c];
            *(ushort4*)(dst + (size_t)c * CDIM + r4) = o;
        }
        return;
    }
    if (b < 960) {  // stats partials: 512 blocks = (batch,group) x 4 spatial chunks
        __shared__ float rs[4], rss[4];
        int bs = b - 448;
        int bg = bs >> 2, ch = bs & 3;          // bg in [0,128): batch*8+group
        const float* base = x + ((size_t)bg * 64) * NSPAT + ch * 256;
        float s = 0.f, ss = 0.f;
        for (int i = tid; i < 4096; i += 256) {  // 64 rows x 64 float4
            int r = i >> 6, c4 = i & 63;
            float4 v = *(const float4*)(base + (size_t)r * NSPAT + c4 * 4);
            s += v.x + v.y + v.z + v.w;
            ss += v.x * v.x + v.y * v.y + v.z * v.z + v.w * v.w;
        }
#pragma unroll
        for (int off = 32; off; off >>= 1) { s += __shfl_down(s, off); ss += __shfl_down(ss, off); }
        int wave = tid >> 6, lane = tid & 63;
        if (lane == 0) { rs[wave] = s; rss[wave] = ss; }
        __syncthreads();
        if (tid == 0) {
            stats_part[bs * 2]     = rs[0] + rs[1] + rs[2] + rs[3];
            stats_part[bs * 2 + 1] = rss[0] + rss[1] + rss[2] + rss[3];
        }
        return;
    }
    if (b < 992) {  // zero lsums (64KB) + rbuf (64KB, contiguous)
        ((float4*)lsums)[(b - 960) * 256 + tid] = (float4){0.f, 0.f, 0.f, 0.f};
        return;
    }
    if (b < 1000) {  // bpv
        int o0 = (b - 992) * 64;
        int wave = tid >> 6, lane = tid & 63;
        const float4* bvv = (const float4*)(b_qkv + 1024);
        float4 v0 = bvv[lane * 2], v1 = bvv[lane * 2 + 1];
        for (int it = 0; it < 16; ++it) {
            int o = o0 + wave * 16 + it;
            const float4* wr = (const float4*)(w_proj + (size_t)o * CDIM);
            float4 a0 = wr[lane * 2], a1 = wr[lane * 2 + 1];
            float s = a0.x * v0.x + a0.y * v0.y + a0.z * v0.z + a0.w * v0.w
                    + a1.x * v1.x + a1.y * v1.y + a1.z * v1.z + a1.w * v1.w;
#pragma unroll
            for (int off = 32; off; off >>= 1) s += __shfl_down(s, off);
            if (lane == 0) bpv[o] = s;
        }
        return;
    }
    {   // cvec = Wk^T bq  (Wk = w_qkv rows 512..1023, bq = b_qkv[0:512])
        int col = (b - 1000) * 256 + tid;
        float s = 0.f;
        for (int m = 0; m < 512; ++m)
            s += w_qkv[(size_t)(512 + m) * CDIM + col] * b_qkv[m];
        cvec[col] = s;
    }
}

// ================= legacy single-buffer 128x128x64 core (M / Wpv GEMMs, 256 thr) =====
__device__ __forceinline__ void stage_tile(
    const u16* __restrict__ Ab, const u16* __restrict__ Bb, int lda, int ldb,
    int m0, int n0, int k0, u16* As, u16* Bs) {
    int tid = threadIdx.x;
#pragma unroll
    for (int it = 0; it < 4; ++it) {
        int c = it * 256 + tid;
        int r = c >> 3, p = c & 7;
        int kc = p ^ (r & 7);
        load_lds16(Ab + (size_t)(m0 + r) * lda + k0 + (kc << 3), &As[c << 3]);
        load_lds16(Bb + (size_t)(n0 + r) * ldb + k0 + (kc << 3), &Bs[c << 3]);
    }
}

__device__ __forceinline__ void compute_tile(
    const u16* As, const u16* Bs, int wm, int wn, int quad, int lrow,
    floatx4 (&acc)[4][4]) {
#pragma unroll
    for (int s = 0; s < 2; ++s) {
        short8 af[4], bf[4];
#pragma unroll
        for (int i = 0; i < 4; ++i) {
            int R = wm + i * 16 + lrow;
            int p = (s * 4 + quad) ^ (R & 7);
            af[i] = *(const short8*)&As[(R << 6) + (p << 3)];
        }
#pragma unroll
        for (int j = 0; j < 4; ++j) {
            int R = wn + j * 16 + lrow;
            int p = (s * 4 + quad) ^ (R & 7);
            bf[j] = *(const short8*)&Bs[(R << 6) + (p << 3)];
        }
#pragma unroll
        for (int i = 0; i < 4; ++i)
#pragma unroll
            for (int j = 0; j < 4; ++j)
                acc[i][j] = __builtin_amdgcn_mfma_f32_16x16x32_bf16(af[i], bf[j], acc[i][j], 0, 0, 0);
    }
}

__device__ __forceinline__ void gemm_core_sb(
    const u16* __restrict__ Ab, const u16* __restrict__ Bb, int K, int lda, int ldb,
    int m0, int n0, u16* As, u16* Bs, floatx4 (&acc)[4][4]) {
    int tid = threadIdx.x;
    int lane = tid & 63, wave = tid >> 6, quad = lane >> 4, lrow = lane & 15;
    int wm = (wave >> 1) << 6, wn = (wave & 1) << 6;
    for (int k0 = 0; k0 < K; k0 += 64) {
        stage_tile(Ab, Bb, lda, ldb, m0, n0, k0, As, Bs);
        __syncthreads();
        compute_tile(As, Bs, wm, wn, quad, lrow, acc);
        __syncthreads();
    }
}

#define ACC_INIT floatx4 acc[4][4]; \
    _Pragma("unroll") for (int i = 0; i < 4; ++i) \
    _Pragma("unroll") for (int j = 0; j < 4; ++j) acc[i][j] = (floatx4){0.f, 0.f, 0.f, 0.f};

#define EPILOG_IDX int lane = threadIdx.x & 63, wave = threadIdx.x >> 6; \
    int quad = lane >> 4, lrow = lane & 15; \
    int wm = (wave >> 1) << 6, wn = (wave & 1) << 6;

// =====================================================================================
// 256x256x64 8-wave core (512 thr), per-wave 128x64, acc[8][4].
// LDS 128KB double-buffered; XOR-swizzled rows; counted vmcnt(8); 2 barriers/K-tile.
// =====================================================================================
__device__ __forceinline__ void issueA2(
    const u16* __restrict__ Ab, int lda, int m0, int t, int h, u16* smem) {
    int tid = threadIdx.x;
    u16* base = smem + (t & 1) * 16384 + h * 8192;
#pragma unroll
    for (int l = 0; l < 2; ++l) {
        int c = l * 512 + tid;
        int rho = c >> 3, p = c & 7;
        int kc = p ^ (rho & 7);
        int r = ((rho >> 6) << 7) | (h << 6) | (rho & 63);
        load_lds16(Ab + (size_t)(m0 + r) * lda + (t << 6) + (kc << 3), base + (c << 3));
    }
}
__device__ __forceinline__ void issueB2(
    const u16* __restrict__ Bb, int ldb, int n0, int t, int h, u16* smem) {
    int tid = threadIdx.x;
    u16* base = smem + 32768 + (t & 1) * 16384 + h * 8192;
#pragma unroll
    for (int l = 0; l < 2; ++l) {
        int c = l * 512 + tid;
        int rho = c >> 3, p = c & 7;
        int kc = p ^ (rho & 7);
        int r = ((rho >> 5) << 6) | (h << 5) | (rho & 31);
        load_lds16(Bb + (size_t)(n0 + r) * ldb + (t << 6) + (kc << 3), base + (c << 3));
    }
}

__device__ __forceinline__ void gemm256x256(
    const u16* __restrict__ Ab, const u16* __restrict__ Bb, int K, int lda, int ldb,
    int m0, int n0, u16* smem, floatx4 (&acc)[8][4]) {
    int tid = threadIdx.x;
    int lane = tid & 63, wave = tid >> 6;
    int quad = lane >> 4, lrow = lane & 15;
    int wrow = wave >> 2, wcol = wave & 3;
    int nt = K >> 6;
    issueA2(Ab, lda, m0, 0, 0, smem);
    issueA2(Ab, lda, m0, 0, 1, smem);
    issueB2(Bb, ldb, n0, 0, 0, smem);
    issueB2(Bb, ldb, n0, 0, 1, smem);
    for (int t = 0; t < nt; ++t) {
        int slot = t & 1;
        BARRIER;
        if (t + 1 < nt) {
            issueA2(Ab, lda, m0, t + 1, 0, smem);
            issueA2(Ab, lda, m0, t + 1, 1, smem);
            issueB2(Bb, ldb, n0, t + 1, 0, smem);
            issueB2(Bb, ldb, n0, t + 1, 1, smem);
            asm volatile("s_waitcnt vmcnt(8)" ::: "memory");
        } else {
            asm volatile("s_waitcnt vmcnt(0)" ::: "memory");
        }
        BARRIER;
        const u16* Ah = smem + slot * 16384;
        const u16* Bh = smem + 32768 + slot * 16384;
        short8 bf[2][4];
#pragma unroll
        for (int qn = 0; qn < 2; ++qn)
#pragma unroll
            for (int ks = 0; ks < 2; ++ks)
#pragma unroll
                for (int j = 0; j < 2; ++j) {
                    int rho = wcol * 32 + j * 16 + lrow;
                    int p = (ks * 4 + quad) ^ (lrow & 7);
                    bf[qn][ks * 2 + j] = *(const short8*)&Bh[qn * 8192 + (rho << 6) + (p << 3)];
                }
#pragma unroll
        for (int qm = 0; qm < 2; ++qm) {
            short8 af[8];
#pragma unroll
            for (int ks = 0; ks < 2; ++ks)
#pragma unroll
                for (int i = 0; i < 4; ++i) {
                    int rho = wrow * 64 + i * 16 + lrow;
                    int p = (ks * 4 + quad) ^ (lrow & 7);
                    af[ks * 4 + i] = *(const short8*)&Ah[qm * 8192 + (rho << 6) + (p << 3)];
                }
#pragma unroll
            for (int ks = 0; ks < 2; ++ks)
#pragma unroll
                for (int i = 0; i < 4; ++i)
#pragma unroll
                    for (int qn = 0; qn < 2; ++qn)
#pragma unroll
                        for (int j = 0; j < 2; ++j)
                            acc[qm * 4 + i][qn * 2 + j] = __builtin_amdgcn_mfma_f32_16x16x32_bf16(
                                af[ks * 4 + i], bf[qn][ks * 2 + j], acc[qm * 4 + i][qn * 2 + j], 0, 0, 0);
        }
    }
}

// =====================================================================================
// 256x128x64 8-wave core (512 thr): per-wave 64x64, acc[4][4]. (96KB)
// =====================================================================================
__device__ __forceinline__ void issueA4(
    const u16* __restrict__ Ab, int lda, int m0, int t, u16* smem) {
    int tid = threadIdx.x;
    u16* base = smem + (t & 1) * 16384;
#pragma unroll
    for (int l = 0; l < 4; ++l) {
        int c = l * 512 + tid;
        int rho = c >> 3, p = c & 7;
        int kc = p ^ (rho & 7);
        load_lds16(Ab + (size_t)(m0 + rho) * lda + (t << 6) + (kc << 3), base + (c << 3));
    }
}
__device__ __forceinline__ void issueB4(
    const u16* __restrict__ Bb, int ldb, int n0, int t, int h, u16* smem) {
    int tid = threadIdx.x;
    u16* base = smem + 32768 + (t & 1) * 8192 + h * 4096;
    int rho = tid >> 3, p = tid & 7;
    int kc = p ^ (rho & 7);
    int r = ((rho >> 5) << 6) | (h << 5) | (rho & 31);
    load_lds16(Bb + (size_t)(n0 + r) * ldb + (t << 6) + (kc << 3), base + (tid << 3));
}

__device__ __forceinline__ void gemm256x128(
    const u16* __restrict__ Ab, const u16* __restrict__ Bb, int K, int lda, int ldb,
    int m0, int n0, u16* smem, floatx4 (&acc)[4][4]) {
    int tid = threadIdx.x;
    int lane = tid & 63, wave = tid >> 6;
    int quad = lane >> 4, lrow = lane & 15;
    int wrow = wave >> 1, wcol = wave & 1;
    int nt = K >> 6;
    issueA4(Ab, lda, m0, 0, smem);
    issueB4(Bb, ldb, n0, 0, 0, smem);
    issueB4(Bb, ldb, n0, 0, 1, smem);
    for (int t = 0; t < nt; ++t) {
        int slot = t & 1;
        BARRIER;
        if (t + 1 < nt) {
            issueA4(Ab, lda, m0, t + 1, smem);
            issueB4(Bb, ldb, n0, t + 1, 0, smem);
            issueB4(Bb, ldb, n0, t + 1, 1, smem);
            asm volatile("s_waitcnt vmcnt(6)" ::: "memory");
        } else {
            asm volatile("s_waitcnt vmcnt(0)" ::: "memory");
        }
        BARRIER;
        const u16* Ah = smem + slot * 16384;
        const u16* Bh = smem + 32768 + slot * 8192;
        short8 bf[2][4];
#pragma unroll
        for (int qn = 0; qn < 2; ++qn)
#pragma unroll
            for (int ks = 0; ks < 2; ++ks)
#pragma unroll
                for (int j = 0; j < 2; ++j) {
                    int rho = wcol * 32 + j * 16 + lrow;
                    int p = (ks * 4 + quad) ^ (lrow & 7);
                    bf[qn][ks * 2 + j] = *(const short8*)&Bh[qn * 4096 + (rho << 6) + (p << 3)];
                }
        short8 af[8];
#pragma unroll
        for (int ks = 0; ks < 2; ++ks)
#pragma unroll
            for (int i = 0; i < 4; ++i) {
                int rho = wrow * 64 + i * 16 + lrow;
                int p = (ks * 4 + quad) ^ (lrow & 7);
                af[ks * 4 + i] = *(const short8*)&Ah[(rho << 6) + (p << 3)];
            }
#pragma unroll
        for (int ks = 0; ks < 2; ++ks)
#pragma unroll
            for (int i = 0; i < 4; ++i)
#pragma unroll
                for (int qn = 0; qn < 2; ++qn)
#pragma unroll
                    for (int j = 0; j < 2; ++j)
                        acc[i][qn * 2 + j] = __builtin_amdgcn_mfma_f32_16x16x32_bf16(
                            af[ks * 4 + i], bf[qn][ks * 2 + j], acc[i][qn * 2 + j], 0, 0, 0);
    }
}

#define ACC_INIT84 floatx4 acc[8][4]; \
    _Pragma("unroll") for (int i = 0; i < 8; ++i) \
    _Pragma("unroll") for (int j = 0; j < 4; ++j) acc[i][j] = (floatx4){0.f, 0.f, 0.f, 0.f};

#define ACC_INIT44 floatx4 acc[4][4]; \
    _Pragma("unroll") for (int i = 0; i < 4; ++i) \
    _Pragma("unroll") for (int j = 0; j < 4; ++j) acc[i][j] = (floatx4){0.f, 0.f, 0.f, 0.f};

// ================= D2: GN apply+transpose+r-partials (z<16) + M / Wpv GEMMs (z==16) ===
#define TSTR 66
__global__ __launch_bounds__(256) void gn_wpv_kernel(
    const float* __restrict__ x, const float* __restrict__ gamma, const float* __restrict__ beta,
    const float* __restrict__ stats_part, u16* __restrict__ hT,
    const u16* __restrict__ wproj_bf, const u16* __restrict__ wq_t,
    const u16* __restrict__ wk_t, const u16* __restrict__ wv_t, u16* __restrict__ wmega,
    const float* __restrict__ cvec, float* __restrict__ rbuf) {
    __shared__ u16 smem[2 * 128 * 64];
    __shared__ float rp[4][64];
    int tid = threadIdx.x;
    if (blockIdx.z == 16) {
        // y<4: M = wq_t . wk_t^T -> wmega rows 0..511 ; y>=4: Wpv -> rows 512..1023
        if (blockIdx.x >= 4) return;
        bool isM = blockIdx.y < 4;
        int m0 = (isM ? blockIdx.y : blockIdx.y - 4) << 7;
        int n0 = blockIdx.x << 7;
        const u16* Aop = isM ? wq_t : wproj_bf;
        const u16* Bop = isM ? wk_t : wv_t;
        int rbase = isM ? 0 : 512;
        ACC_INIT;
        gemm_core_sb(Aop, Bop, CDIM, CDIM, CDIM, m0, n0, smem, smem + 128 * 64, acc);
        EPILOG_IDX;
#pragma unroll
        for (int i = 0; i < 4; ++i)
#pragma unroll
            for (int j = 0; j < 4; ++j)
#pragma unroll
                for (int r = 0; r < 4; ++r) {
                    int R = m0 + wm + i * 16 + (quad << 2) + r;
                    int Cc = n0 + wn + j * 16 + lrow;
                    wmega[(size_t)(rbase + R) * CDIM + Cc] = f2bf(acc[i][j][r]);
                }
        return;
    }
    u16* t = smem;
    int b = blockIdx.z, c0 = blockIdx.y << 6, n0 = blockIdx.x << 6;
    // group stats from 4 partials (this tile's 64 channels = exactly one group)
    int bg4 = (b * NGROUP + (c0 >> 6)) * 4;
    float s1 = stats_part[(bg4 + 0) * 2] + stats_part[(bg4 + 1) * 2]
             + stats_part[(bg4 + 2) * 2] + stats_part[(bg4 + 3) * 2];
    float s2 = stats_part[(bg4 + 0) * 2 + 1] + stats_part[(bg4 + 1) * 2 + 1]
             + stats_part[(bg4 + 2) * 2 + 1] + stats_part[(bg4 + 3) * 2 + 1];
    float mean = s1 * (1.f / 65536.f);
    float var = s2 * (1.f / 65536.f) - mean * mean;
    float rsq = rsqrtf(var + 1e-5f);
    const float* xb = x + ((size_t)b * CDIM + c0) * NSPAT + n0;
#pragma unroll
    for (int p = 0; p < 4; ++p) {
        int cl = p * 16 + (tid >> 4);
        int nl = (tid & 15) << 2;
        int c = c0 + cl;
        float ga = gamma[c] * rsq;
        float be = beta[c] - mean * ga;
        float4 v = *(const float4*)(xb + (size_t)cl * NSPAT + nl);
        u16* dst = &t[cl * TSTR + nl];
        dst[0] = f2bf(v.x * ga + be);
        dst[1] = f2bf(v.y * ga + be);
        dst[2] = f2bf(v.z * ga + be);
        dst[3] = f2bf(v.w * ga + be);
    }
    __syncthreads();
    // r partials: r_j += sum_{cl} cvec[c0+cl] * h[cl][j]   (tile is resident in LDS)
    {
        int j = tid & 63, part = tid >> 6;
        float rs_ = 0.f;
#pragma unroll
        for (int q = 0; q < 16; ++q) {
            int cl = part * 16 + q;
            rs_ += cvec[c0 + cl] * bf2f(t[cl * TSTR + j]);
        }
        rp[part][j] = rs_;
    }
    __syncthreads();
    if (tid < 64) {
        float s = rp[0][tid] + rp[1][tid] + rp[2][tid] + rp[3][tid];
        atomicAdd(&rbuf[(size_t)b * NSPAT + n0 + tid], s);
    }
    u16* hb = hT + ((size_t)b * NSPAT + n0) * CDIM + c0;
#pragma unroll
    for (int p = 0; p < 4; ++p) {
        int nl = p * 16 + (tid >> 4);
        int cl4 = (tid & 15) << 2;
        ushort4 o;
        o.x = t[(cl4 + 0) * TSTR + nl];
        o.y = t[(cl4 + 1) * TSTR + nl];
        o.z = t[(cl4 + 2) * TSTR + nl];
        o.w = t[(cl4 + 3) * TSTR + nl];
        *(ushort4*)(hb + (size_t)nl * CDIM + cl4) = o;
    }
}

// ================= D3: gwv: [g; WV] = wmega . h  (+bpv on WV rows) ====================
// grid (BATCH, 4, 4), 512 thr: y = n-tile(256), z = m-tile(256) of [g(2); WV(2)].
// 256 blocks = exactly 1.0 round.
__global__ __launch_bounds__(512, 2) void qkv_kernel(
    const u16* __restrict__ wmega, const u16* __restrict__ hT,
    const float* __restrict__ bpv,
    u16* __restrict__ gT, u16* __restrict__ WV) {
    extern __shared__ u16 smem[];
    int z = blockIdx.x;
    int n0 = blockIdx.y << 8;
    int m0 = blockIdx.z << 8;
    const u16* Bb = hT + (size_t)z * CDIM * NSPAT;
    ACC_INIT84;
    gemm256x256(wmega, Bb, CDIM, CDIM, CDIM, m0, n0, smem, acc);
    int lane = threadIdx.x & 63, wave = threadIdx.x >> 6;
    int quad = lane >> 4, lrow = lane & 15;
    int wrow = wave >> 2, wcol = wave & 3;
    if (blockIdx.z < 2) {  // g rows: transposed packed store to gT[n][c], ldc=512, NO bias
        u16* gp = gT + (size_t)z * NSPAT * CDIM;
#pragma unroll
        for (int mf = 0; mf < 8; ++mf) {
            int R0 = m0 + wrow * 128 + mf * 16 + (quad << 2);
#pragma unroll
            for (int nf = 0; nf < 4; ++nf) {
                int Cc = n0 + wcol * 64 + nf * 16 + lrow;
                uint2 u;
                u.x = f2bf2(acc[mf][nf][0], acc[mf][nf][1]);
                u.y = f2bf2(acc[mf][nf][2], acc[mf][nf][3]);
                *(uint2*)&gp[(size_t)Cc * CDIM + R0] = u;
            }
        }
    } else {  // WV rows: natural store WV[o][n] + bpv
        u16* Wp = WV + (size_t)z * CDIM * NSPAT;
#pragma unroll
        for (int mf = 0; mf < 8; ++mf) {
            int R = m0 - 512 + wrow * 128 + mf * 16 + (quad << 2);
            float4 pv = *(const float4*)&bpv[R];
#pragma unroll
            for (int nf = 0; nf < 4; ++nf) {
                int Cc = n0 + wcol * 64 + nf * 16 + lrow;
                Wp[(size_t)(R + 0) * NSPAT + Cc] = f2bf(acc[mf][nf][0] + pv.x);
                Wp[(size_t)(R + 1) * NSPAT + Cc] = f2bf(acc[mf][nf][1] + pv.y);
                Wp[(size_t)(R + 2) * NSPAT + Cc] = f2bf(acc[mf][nf][2] + pv.z);
                Wp[(size_t)(R + 3) * NSPAT + Cc] = f2bf(acc[mf][nf][3] + pv.w);
            }
        }
    }
}

// ================= D4: scores: D[j][i] = g_j . h_i  (+ r_j), exp, row-sums ============
// grid (BATCH, 4, 4), 512 thr: y = i-tile(256), z = j-tile(256).
__global__ __launch_bounds__(512, 2) void scores_kernel(
    const u16* __restrict__ gT, const u16* __restrict__ hT,
    u16* __restrict__ P, float* __restrict__ lsums, const float* __restrict__ rbuf,
    float scale) {
    extern __shared__ u16 smem[];
    int z = blockIdx.x;
    int n0 = blockIdx.y << 8;                // i tile (N-dim)
    int m0 = blockIdx.z << 8;                // j tile (M-dim)
    const u16* gb = gT + (size_t)z * NSPAT * CDIM;
    const u16* hb = hT + (size_t)z * CDIM * NSPAT;
    ACC_INIT84;
    gemm256x256(gb, hb, CDIM, CDIM, CDIM, m0, n0, smem, acc);
    int lane = threadIdx.x & 63, wave = threadIdx.x >> 6;
    int quad = lane >> 4, lrow = lane & 15;
    int wrow = wave >> 2, wcol = wave & 3;
    u16* Pp = P + (size_t)z * NSPAT * NSPAT;
    float* ls = lsums + (size_t)z * NSPAT;
    const float* rb = rbuf + (size_t)z * NSPAT;
#pragma unroll
    for (int nf = 0; nf < 4; ++nf) {
        int Ci = n0 + wcol * 64 + nf * 16 + lrow;    // i (column of D)
        float part = 0.f;
#pragma unroll
        for (int mf = 0; mf < 8; ++mf) {
            int Rj0 = m0 + wrow * 128 + mf * 16 + (quad << 2);   // j rows, 4 consecutive
            float4 rv = *(const float4*)&rb[Rj0];
            float e0 = __expf((acc[mf][nf][0] + rv.x) * scale);
            float e1 = __expf((acc[mf][nf][1] + rv.y) * scale);
            float e2 = __expf((acc[mf][nf][2] + rv.z) * scale);
            float e3 = __expf((acc[mf][nf][3] + rv.w) * scale);
            part += (e0 + e1) + (e2 + e3);
            uint2 u;
            u.x = f2bf2(e0, e1);
            u.y = f2bf2(e2, e3);
            *(uint2*)&Pp[(size_t)Ci * NSPAT + Rj0] = u;
        }
        part += __shfl_xor(part, 16);
        part += __shfl_xor(part, 32);
        if (lane < 16) atomicAdd(&ls[Ci], part);
    }
}

// ================= D5: final (swapped operands): D[i][o] = P_i . WV_o =================
// grid (BATCH, 4, 4), 512 thr: y = o-tile(128), z = i-tile(256).
__global__ __launch_bounds__(512, 2) void final_kernel(
    const u16* __restrict__ WV, const u16* __restrict__ P, const float* __restrict__ lsums,
    const float* __restrict__ bias, const float* __restrict__ x, float* __restrict__ out) {
    extern __shared__ u16 smem[];
    int z = blockIdx.x;
    int n0 = blockIdx.y << 7;                // o tile (N-dim, 4 tiles of 128)
    int m0 = blockIdx.z << 8;                // i tile (M-dim, 4 tiles of 256)
    const u16* Pb = P + (size_t)z * NSPAT * NSPAT;
    const u16* WVb = WV + (size_t)z * CDIM * NSPAT;
    ACC_INIT44;
    gemm256x128(Pb, WVb, NSPAT, NSPAT, NSPAT, m0, n0, smem, acc);
    int lane = threadIdx.x & 63, wave = threadIdx.x >> 6;
    int quad = lane >> 4, lrow = lane & 15;
    int wrow = wave >> 1, wcol = wave & 1;
    float* Op = out + (size_t)z * CDIM * NSPAT;
    const float* xr = x + (size_t)z * CDIM * NSPAT;
    const float* li = lsums + (size_t)z * NSPAT;
#pragma unroll
    for (int mf = 0; mf < 4; ++mf) {
        int Ri0 = m0 + wrow * 64 + mf * 16 + (quad << 2);        // i, 4 consecutive
        float4 lv = *(const float4*)&li[Ri0];
        float s0 = __builtin_amdgcn_rcpf(lv.x);
        float s1 = __builtin_amdgcn_rcpf(lv.y);
        float s2 = __builtin_amdgcn_rcpf(lv.z);
        float s3 = __builtin_amdgcn_rcpf(lv.w);
#pragma unroll
        for (int nf = 0; nf < 4; ++nf) {
            int Co = n0 + wcol * 64 + nf * 16 + lrow;            // o
            float bv = bias[Co];
            size_t off = (size_t)Co * NSPAT + Ri0;
            float4 xv = *(const float4*)&xr[off];
            float4 o;
            o.x = acc[mf][nf][0] * s0 + bv + xv.x;
            o.y = acc[mf][nf][1] * s1 + bv + xv.y;
            o.z = acc[mf][nf][2] * s2 + bv + xv.z;
            o.w = acc[mf][nf][3] * s3 + bv + xv.w;
            *(float4*)&Op[off] = o;
        }
    }
}

// ================= launch =================
extern "C" void kernel_launch(void* const* d_in, const int* in_sizes, int n_in,
                              void* d_out, int out_size, void* d_ws, size_t ws_size,
                              hipStream_t stream) {
    const float* x      = (const float*)d_in[0];
    const float* gamma  = (const float*)d_in[1];
    const float* beta   = (const float*)d_in[2];
    const float* w_qkv  = (const float*)d_in[3];
    const float* b_qkv  = (const float*)d_in[4];
    const float* w_proj = (const float*)d_in[5];
    const float* b_proj = (const float*)d_in[6];
    float* out = (float*)d_out;

    const size_t CN = (size_t)CDIM * NSPAT;   // 524288
    const size_t NN = (size_t)NSPAT * NSPAT;  // 1048576
    const float SCALE = 0.044194173824159216f;
    const int LDS_BIG = 131072;   // 256x256 core
    const int LDS_MED = 98304;    // 256x128 core

    static bool lds_attr_done = false;
    if (!lds_attr_done) {
        hipFuncSetAttribute((const void*)qkv_kernel,
                            hipFuncAttributeMaxDynamicSharedMemorySize, LDS_BIG);
        hipFuncSetAttribute((const void*)scores_kernel,
                            hipFuncAttributeMaxDynamicSharedMemorySize, LDS_BIG);
        hipFuncSetAttribute((const void*)final_kernel,
                            hipFuncAttributeMaxDynamicSharedMemorySize, LDS_MED);
        lds_attr_done = true;
    }

    char* ws = (char*)d_ws;
    float* stats_part = (float*)ws;                           // 512x2 floats = 4 KB
    float* bpv     = (float*)(ws + 4096);                     // 2 KB
    float* cvec    = (float*)(ws + 6144);                     // 2 KB
    u16* wmega     = (u16*)(ws + 8192);                       // [M; Wpv] 1024x512 bf16 (1MB)
    u16* wproj_bf  = wmega + (size_t)1024 * CDIM;             // 0.5 MB
    u16* wq_t      = wproj_bf + (size_t)CDIM * CDIM;          // 0.5 MB
    u16* wk_t      = wq_t + (size_t)CDIM * CDIM;              // 0.5 MB
    u16* wv_t      = wk_t + (size_t)CDIM * CDIM;              // 0.5 MB
    u16* hT        = wv_t + (size_t)CDIM * CDIM;              // 16.8 MB [n][c]
    u16* gT        = hT + BATCH * CN;                         // 16.8 MB [n][c]
    u16* WV        = gT + BATCH * CN;                         // 16.8 MB [o][n]
    u16* P         = WV + BATCH * CN;                         // 33.5 MB [i][j] unnorm
    float* lsums   = (float*)(P + BATCH * NN);                // 64 KB
    float* rbuf    = lsums + (size_t)BATCH * NSPAT;           // 64 KB (contiguous after lsums)

    prep_kernel<<<1002, 256, 0, stream>>>(
        w_qkv, w_proj, b_qkv, x, wproj_bf, wq_t, wk_t, wv_t, stats_part, lsums, bpv, cvec);

    gn_wpv_kernel<<<dim3(16, 8, 17), 256, 0, stream>>>(
        x, gamma, beta, stats_part, hT, wproj_bf, wq_t, wk_t, wv_t, wmega, cvec, rbuf);

    qkv_kernel<<<dim3(BATCH, 4, 4), 512, LDS_BIG, stream>>>(
        wmega, hT, bpv, gT, WV);

    scores_kernel<<<dim3(BATCH, 4, 4), 512, LDS_BIG, stream>>>(
        gT, hT, P, lsums, rbuf, SCALE);

    final_kernel<<<dim3(BATCH, 4, 4), 512, LDS_MED, stream>>>(WV, P, lsums, b_proj, x, out);
}

// Round 12
// 124.932 us; speedup vs baseline: 1.0384x; 1.0384x over previous
//
#include <hip/hip_runtime.h>
#include <hip/hip_bf16.h>

typedef unsigned short u16;
typedef unsigned int u32;
typedef __attribute__((ext_vector_type(8))) short short8;
typedef __attribute__((ext_vector_type(4))) float floatx4;

#define BATCH 16
#define CDIM 512
#define NSPAT 1024
#define NGROUP 8

__device__ __forceinline__ u16 f2bf(float f) {
    unsigned u = __float_as_uint(f);
    u += 0x7FFFu + ((u >> 16) & 1u);   // RNE
    return (u16)(u >> 16);
}
__device__ __forceinline__ u32 f2bf2(float lo, float hi) {   // packed v_cvt_pk_bf16_f32
    __hip_bfloat162 h = __float22bfloat162_rn(make_float2(lo, hi));
    return *(u32*)&h;
}
__device__ __forceinline__ float bf2f(u16 v) {
    u32 t = ((u32)v) << 16;
    return __uint_as_float(t);
}

__device__ __forceinline__ void load_lds16(const void* g, void* l) {
    __builtin_amdgcn_global_load_lds(
        (const __attribute__((address_space(1))) unsigned int*)g,
        (__attribute__((address_space(3))) unsigned int*)l, 16, 0, 0);
}

#define SBAR0 __builtin_amdgcn_sched_barrier(0)
#define BARRIER { SBAR0; __builtin_amdgcn_s_barrier(); SBAR0; }

// ================= D1 prep =================
// blocks [0,256):    w_proj cvt -> wproj_bf
//        [256,448):  transpose wq/wk/wv -> wq_t/wk_t/wv_t (64x64 tiles)
//        [448,960):  GroupNorm partial sums (4 spatial chunks per (batch,group))
//        [960,992):  zero lsums+rbuf (contiguous 128KB)
//        [992,1000): bpv[o] = sum_c w_proj[o][c] * b_qkv[1024+c]
//        [1000,1002): cvec[b] = sum_m w_qkv[512+m][b] * b_qkv[m]   (c = Wk^T bq)
__global__ __launch_bounds__(256) void prep_kernel(
    const float* __restrict__ w_qkv, const float* __restrict__ w_proj,
    const float* __restrict__ b_qkv, const float* __restrict__ x,
    u16* __restrict__ wproj_bf, u16* __restrict__ wq_t, u16* __restrict__ wk_t,
    u16* __restrict__ wv_t, float* __restrict__ stats_part, float* __restrict__ lsums,
    float* __restrict__ bpv, float* __restrict__ cvec) {
    int b = blockIdx.x;
    int tid = threadIdx.x;
    if (b < 256) {  // w_proj -> bf16
        int i = b * 256 + tid;
        float4 v = ((const float4*)w_proj)[i];
        u32* d = (u32*)wproj_bf;
        d[i * 2] = f2bf2(v.x, v.y);
        d[i * 2 + 1] = f2bf2(v.z, v.w);
        return;
    }
    if (b < 448) {  // transpose w_qkv section -> *_t[ci][m], 64x64 tiles
        __shared__ u16 t[64 * 66];
        int bt = b - 256;
        int which = bt >> 6;            // 0=wq, 1=wk, 2=wv
        int bt2 = bt & 63;
        int tx = bt2 & 7, ty = bt2 >> 3;
        const float* src = w_qkv + (size_t)(which * 512 + ty * 64) * CDIM + tx * 64;
        u16* dstb = (which == 0) ? wq_t : (which == 1) ? wk_t : wv_t;
#pragma unroll
        for (int p = 0; p < 4; ++p) {
            int r = p * 16 + (tid >> 4);
            int c4 = (tid & 15) << 2;
            float4 v = *(const float4*)(src + (size_t)r * CDIM + c4);
            u16* d = &t[r * 66 + c4];
            d[0] = f2bf(v.x); d[1] = f2bf(v.y); d[2] = f2bf(v.z); d[3] = f2bf(v.w);
        }
        __syncthreads();
        u16* dst = dstb + (size_t)(tx * 64) * CDIM + ty * 64;
#pragma unroll
        for (int p = 0; p < 4; ++p) {
            int c = p * 16 + (tid >> 4);
            int r4 = (tid & 15) << 2;
            ushort4 o;
            o.x = t[(r4 + 0) * 66 + c];
            o.y = t[(r4 + 1) * 66 + c];
            o.z = t[(r4 + 2) * 66 + c];
            o.w = t[(r4 + 3) * 66 + c];
            *(ushort4*)(dst + (size_t)c * CDIM + r4) = o;
        }
        return;
    }
    if (b < 960) {  // stats partials: 512 blocks = (batch,group) x 4 spatial chunks
        __shared__ float rs[4], rss[4];
        int bs = b - 448;
        int bg = bs >> 2, ch = bs & 3;          // bg in [0,128): batch*8+group
        const float* base = x + ((size_t)bg * 64) * NSPAT + ch * 256;
        float s = 0.f, ss = 0.f;
        for (int i = tid; i < 4096; i += 256) {  // 64 rows x 64 float4
            int r = i >> 6, c4 = i & 63;
            float4 v = *(const float4*)(base + (size_t)r * NSPAT + c4 * 4);
            s += v.x + v.y + v.z + v.w;
            ss += v.x * v.x + v.y * v.y + v.z * v.z + v.w * v.w;
        }
#pragma unroll
        for (int off = 32; off; off >>= 1) { s += __shfl_down(s, off); ss += __shfl_down(ss, off); }
        int wave = tid >> 6, lane = tid & 63;
        if (lane == 0) { rs[wave] = s; rss[wave] = ss; }
        __syncthreads();
        if (tid == 0) {
            stats_part[bs * 2]     = rs[0] + rs[1] + rs[2] + rs[3];
            stats_part[bs * 2 + 1] = rss[0] + rss[1] + rss[2] + rss[3];
        }
        return;
    }
    if (b < 992) {  // zero lsums (64KB) + rbuf (64KB, contiguous)
        ((float4*)lsums)[(b - 960) * 256 + tid] = (float4){0.f, 0.f, 0.f, 0.f};
        return;
    }
    if (b < 1000) {  // bpv
        int o0 = (b - 992) * 64;
        int wave = tid >> 6, lane = tid & 63;
        const float4* bvv = (const float4*)(b_qkv + 1024);
        float4 v0 = bvv[lane * 2], v1 = bvv[lane * 2 + 1];
        for (int it = 0; it < 16; ++it) {
            int o = o0 + wave * 16 + it;
            const float4* wr = (const float4*)(w_proj + (size_t)o * CDIM);
            float4 a0 = wr[lane * 2], a1 = wr[lane * 2 + 1];
            float s = a0.x * v0.x + a0.y * v0.y + a0.z * v0.z + a0.w * v0.w
                    + a1.x * v1.x + a1.y * v1.y + a1.z * v1.z + a1.w * v1.w;
#pragma unroll
            for (int off = 32; off; off >>= 1) s += __shfl_down(s, off);
            if (lane == 0) bpv[o] = s;
        }
        return;
    }
    {   // cvec = Wk^T bq  (Wk = w_qkv rows 512..1023, bq = b_qkv[0:512])
        int col = (b - 1000) * 256 + tid;
        float s = 0.f;
        for (int m = 0; m < 512; ++m)
            s += w_qkv[(size_t)(512 + m) * CDIM + col] * b_qkv[m];
        cvec[col] = s;
    }
}

// =====================================================================================
// 256x256x64 8-wave core (512 thr), per-wave 128x64, acc[8][4].
// LDS 128KB double-buffered; XOR-swizzled rows; counted vmcnt(8); 2 barriers/K-tile.
// =====================================================================================
__device__ __forceinline__ void issueA2(
    const u16* __restrict__ Ab, int lda, int m0, int t, int h, u16* smem) {
    int tid = threadIdx.x;
    u16* base = smem + (t & 1) * 16384 + h * 8192;
#pragma unroll
    for (int l = 0; l < 2; ++l) {
        int c = l * 512 + tid;
        int rho = c >> 3, p = c & 7;
        int kc = p ^ (rho & 7);
        int r = ((rho >> 6) << 7) | (h << 6) | (rho & 63);
        load_lds16(Ab + (size_t)(m0 + r) * lda + (t << 6) + (kc << 3), base + (c << 3));
    }
}
__device__ __forceinline__ void issueB2(
    const u16* __restrict__ Bb, int ldb, int n0, int t, int h, u16* smem) {
    int tid = threadIdx.x;
    u16* base = smem + 32768 + (t & 1) * 16384 + h * 8192;
#pragma unroll
    for (int l = 0; l < 2; ++l) {
        int c = l * 512 + tid;
        int rho = c >> 3, p = c & 7;
        int kc = p ^ (rho & 7);
        int r = ((rho >> 5) << 6) | (h << 5) | (rho & 31);
        load_lds16(Bb + (size_t)(n0 + r) * ldb + (t << 6) + (kc << 3), base + (c << 3));
    }
}

__device__ __forceinline__ void gemm256x256(
    const u16* __restrict__ Ab, const u16* __restrict__ Bb, int K, int lda, int ldb,
    int m0, int n0, u16* smem, floatx4 (&acc)[8][4]) {
    int tid = threadIdx.x;
    int lane = tid & 63, wave = tid >> 6;
    int quad = lane >> 4, lrow = lane & 15;
    int wrow = wave >> 2, wcol = wave & 3;
    int nt = K >> 6;
    issueA2(Ab, lda, m0, 0, 0, smem);
    issueA2(Ab, lda, m0, 0, 1, smem);
    issueB2(Bb, ldb, n0, 0, 0, smem);
    issueB2(Bb, ldb, n0, 0, 1, smem);
    for (int t = 0; t < nt; ++t) {
        int slot = t & 1;
        BARRIER;
        if (t + 1 < nt) {
            issueA2(Ab, lda, m0, t + 1, 0, smem);
            issueA2(Ab, lda, m0, t + 1, 1, smem);
            issueB2(Bb, ldb, n0, t + 1, 0, smem);
            issueB2(Bb, ldb, n0, t + 1, 1, smem);
            asm volatile("s_waitcnt vmcnt(8)" ::: "memory");
        } else {
            asm volatile("s_waitcnt vmcnt(0)" ::: "memory");
        }
        BARRIER;
        const u16* Ah = smem + slot * 16384;
        const u16* Bh = smem + 32768 + slot * 16384;
        short8 bf[2][4];
#pragma unroll
        for (int qn = 0; qn < 2; ++qn)
#pragma unroll
            for (int ks = 0; ks < 2; ++ks)
#pragma unroll
                for (int j = 0; j < 2; ++j) {
                    int rho = wcol * 32 + j * 16 + lrow;
                    int p = (ks * 4 + quad) ^ (lrow & 7);
                    bf[qn][ks * 2 + j] = *(const short8*)&Bh[qn * 8192 + (rho << 6) + (p << 3)];
                }
#pragma unroll
        for (int qm = 0; qm < 2; ++qm) {
            short8 af[8];
#pragma unroll
            for (int ks = 0; ks < 2; ++ks)
#pragma unroll
                for (int i = 0; i < 4; ++i) {
                    int rho = wrow * 64 + i * 16 + lrow;
                    int p = (ks * 4 + quad) ^ (lrow & 7);
                    af[ks * 4 + i] = *(const short8*)&Ah[qm * 8192 + (rho << 6) + (p << 3)];
                }
#pragma unroll
            for (int ks = 0; ks < 2; ++ks)
#pragma unroll
                for (int i = 0; i < 4; ++i)
#pragma unroll
                    for (int qn = 0; qn < 2; ++qn)
#pragma unroll
                        for (int j = 0; j < 2; ++j)
                            acc[qm * 4 + i][qn * 2 + j] = __builtin_amdgcn_mfma_f32_16x16x32_bf16(
                                af[ks * 4 + i], bf[qn][ks * 2 + j], acc[qm * 4 + i][qn * 2 + j], 0, 0, 0);
        }
    }
}

// =====================================================================================
// 256x128x64 8-wave core (512 thr): per-wave 64x64, acc[4][4]. (96KB)
// =====================================================================================
__device__ __forceinline__ void issueA4(
    const u16* __restrict__ Ab, int lda, int m0, int t, u16* smem) {
    int tid = threadIdx.x;
    u16* base = smem + (t & 1) * 16384;
#pragma unroll
    for (int l = 0; l < 4; ++l) {
        int c = l * 512 + tid;
        int rho = c >> 3, p = c & 7;
        int kc = p ^ (rho & 7);
        load_lds16(Ab + (size_t)(m0 + rho) * lda + (t << 6) + (kc << 3), base + (c << 3));
    }
}
__device__ __forceinline__ void issueB4(
    const u16* __restrict__ Bb, int ldb, int n0, int t, int h, u16* smem) {
    int tid = threadIdx.x;
    u16* base = smem + 32768 + (t & 1) * 8192 + h * 4096;
    int rho = tid >> 3, p = tid & 7;
    int kc = p ^ (rho & 7);
    int r = ((rho >> 5) << 6) | (h << 5) | (rho & 31);
    load_lds16(Bb + (size_t)(n0 + r) * ldb + (t << 6) + (kc << 3), base + (tid << 3));
}

__device__ __forceinline__ void gemm256x128(
    const u16* __restrict__ Ab, const u16* __restrict__ Bb, int K, int lda, int ldb,
    int m0, int n0, u16* smem, floatx4 (&acc)[4][4]) {
    int tid = threadIdx.x;
    int lane = tid & 63, wave = tid >> 6;
    int quad = lane >> 4, lrow = lane & 15;
    int wrow = wave >> 1, wcol = wave & 1;
    int nt = K >> 6;
    issueA4(Ab, lda, m0, 0, smem);
    issueB4(Bb, ldb, n0, 0, 0, smem);
    issueB4(Bb, ldb, n0, 0, 1, smem);
    for (int t = 0; t < nt; ++t) {
        int slot = t & 1;
        BARRIER;
        if (t + 1 < nt) {
            issueA4(Ab, lda, m0, t + 1, smem);
            issueB4(Bb, ldb, n0, t + 1, 0, smem);
            issueB4(Bb, ldb, n0, t + 1, 1, smem);
            asm volatile("s_waitcnt vmcnt(6)" ::: "memory");
        } else {
            asm volatile("s_waitcnt vmcnt(0)" ::: "memory");
        }
        BARRIER;
        const u16* Ah = smem + slot * 16384;
        const u16* Bh = smem + 32768 + slot * 8192;
        short8 bf[2][4];
#pragma unroll
        for (int qn = 0; qn < 2; ++qn)
#pragma unroll
            for (int ks = 0; ks < 2; ++ks)
#pragma unroll
                for (int j = 0; j < 2; ++j) {
                    int rho = wcol * 32 + j * 16 + lrow;
                    int p = (ks * 4 + quad) ^ (lrow & 7);
                    bf[qn][ks * 2 + j] = *(const short8*)&Bh[qn * 4096 + (rho << 6) + (p << 3)];
                }
        short8 af[8];
#pragma unroll
        for (int ks = 0; ks < 2; ++ks)
#pragma unroll
            for (int i = 0; i < 4; ++i) {
                int rho = wrow * 64 + i * 16 + lrow;
                int p = (ks * 4 + quad) ^ (lrow & 7);
                af[ks * 4 + i] = *(const short8*)&Ah[(rho << 6) + (p << 3)];
            }
#pragma unroll
        for (int ks = 0; ks < 2; ++ks)
#pragma unroll
            for (int i = 0; i < 4; ++i)
#pragma unroll
                for (int qn = 0; qn < 2; ++qn)
#pragma unroll
                    for (int j = 0; j < 2; ++j)
                        acc[i][qn * 2 + j] = __builtin_amdgcn_mfma_f32_16x16x32_bf16(
                            af[ks * 4 + i], bf[qn][ks * 2 + j], acc[i][qn * 2 + j], 0, 0, 0);
    }
}

#define ACC_INIT84 floatx4 acc[8][4]; \
    _Pragma("unroll") for (int i = 0; i < 8; ++i) \
    _Pragma("unroll") for (int j = 0; j < 4; ++j) acc[i][j] = (floatx4){0.f, 0.f, 0.f, 0.f};

#define ACC_INIT44 floatx4 acc[4][4]; \
    _Pragma("unroll") for (int i = 0; i < 4; ++i) \
    _Pragma("unroll") for (int j = 0; j < 4; ++j) acc[i][j] = (floatx4){0.f, 0.f, 0.f, 0.f};

// ================= D2: GN apply+transpose+r-partials (z<16) + M / Wpv GEMMs (z==16) ===
// z==16: 128 blocks (16x8 xy-grid), each a 64x64x512 4-wave GEMM tile.
//   idx = y*16+x; idx<64: M = wq_t . wk_t^T -> wmega rows 0..511
//                 idx>=64: Wpv = wproj_bf . wv_t^T -> wmega rows 512..1023
#define TSTR 66
__global__ __launch_bounds__(256) void gn_wpv_kernel(
    const float* __restrict__ x, const float* __restrict__ gamma, const float* __restrict__ beta,
    const float* __restrict__ stats_part, u16* __restrict__ hT,
    const u16* __restrict__ wproj_bf, const u16* __restrict__ wq_t,
    const u16* __restrict__ wk_t, const u16* __restrict__ wv_t, u16* __restrict__ wmega,
    const float* __restrict__ cvec, float* __restrict__ rbuf) {
    __shared__ u16 smem[2 * 128 * 64];
    __shared__ float rp[4][64];
    int tid = threadIdx.x;
    if (blockIdx.z == 16) {
        int idx = blockIdx.y * 16 + blockIdx.x;      // [0,128)
        bool isM = idx < 64;
        int tilei = idx & 63;
        int m0 = (tilei >> 3) * 64, n0 = (tilei & 7) * 64;
        const u16* Aop = isM ? wq_t : wproj_bf;
        const u16* Bop = isM ? wk_t : wv_t;
        int rbase = isM ? 0 : 512;
        u16* As = smem;                 // 64x64 u16 = 8KB
        u16* Bs = smem + 4096;
        int lane = tid & 63, wave = tid >> 6;
        int quad = lane >> 4, lrow = lane & 15;
        int wrow = wave >> 1, wcol = wave & 1;
        floatx4 acc[2][2];
#pragma unroll
        for (int i = 0; i < 2; ++i)
#pragma unroll
            for (int j = 0; j < 2; ++j) acc[i][j] = (floatx4){0.f, 0.f, 0.f, 0.f};
        for (int k0 = 0; k0 < CDIM; k0 += 64) {
#pragma unroll
            for (int l = 0; l < 2; ++l) {
                int c = l * 256 + tid;
                int rho = c >> 3, p = c & 7;
                int kc = p ^ (rho & 7);
                load_lds16(Aop + (size_t)(m0 + rho) * CDIM + k0 + (kc << 3), &As[c << 3]);
                load_lds16(Bop + (size_t)(n0 + rho) * CDIM + k0 + (kc << 3), &Bs[c << 3]);
            }
            __syncthreads();
#pragma unroll
            for (int ks = 0; ks < 2; ++ks) {
                short8 af[2], bf[2];
#pragma unroll
                for (int i = 0; i < 2; ++i) {
                    int R = wrow * 32 + i * 16 + lrow;
                    int p = (ks * 4 + quad) ^ (lrow & 7);
                    af[i] = *(const short8*)&As[(R << 6) + (p << 3)];
                }
#pragma unroll
                for (int j = 0; j < 2; ++j) {
                    int R = wcol * 32 + j * 16 + lrow;
                    int p = (ks * 4 + quad) ^ (lrow & 7);
                    bf[j] = *(const short8*)&Bs[(R << 6) + (p << 3)];
                }
#pragma unroll
                for (int i = 0; i < 2; ++i)
#pragma unroll
                    for (int j = 0; j < 2; ++j)
                        acc[i][j] = __builtin_amdgcn_mfma_f32_16x16x32_bf16(af[i], bf[j], acc[i][j], 0, 0, 0);
            }
            __syncthreads();
        }
#pragma unroll
        for (int i = 0; i < 2; ++i)
#pragma unroll
            for (int j = 0; j < 2; ++j)
#pragma unroll
                for (int r = 0; r < 4; ++r) {
                    int R = m0 + wrow * 32 + i * 16 + (quad << 2) + r;
                    int Cc = n0 + wcol * 32 + j * 16 + lrow;
                    wmega[(size_t)(rbase + R) * CDIM + Cc] = f2bf(acc[i][j][r]);
                }
        return;
    }
    u16* t = smem;
    int b = blockIdx.z, c0 = blockIdx.y << 6, n0 = blockIdx.x << 6;
    // group stats from 4 partials (this tile's 64 channels = exactly one group)
    int bg4 = (b * NGROUP + (c0 >> 6)) * 4;
    float s1 = stats_part[(bg4 + 0) * 2] + stats_part[(bg4 + 1) * 2]
             + stats_part[(bg4 + 2) * 2] + stats_part[(bg4 + 3) * 2];
    float s2 = stats_part[(bg4 + 0) * 2 + 1] + stats_part[(bg4 + 1) * 2 + 1]
             + stats_part[(bg4 + 2) * 2 + 1] + stats_part[(bg4 + 3) * 2 + 1];
    float mean = s1 * (1.f / 65536.f);
    float var = s2 * (1.f / 65536.f) - mean * mean;
    float rsq = rsqrtf(var + 1e-5f);
    const float* xb = x + ((size_t)b * CDIM + c0) * NSPAT + n0;
#pragma unroll
    for (int p = 0; p < 4; ++p) {
        int cl = p * 16 + (tid >> 4);
        int nl = (tid & 15) << 2;
        int c = c0 + cl;
        float ga = gamma[c] * rsq;
        float be = beta[c] - mean * ga;
        float4 v = *(const float4*)(xb + (size_t)cl * NSPAT + nl);
        u16* dst = &t[cl * TSTR + nl];
        dst[0] = f2bf(v.x * ga + be);
        dst[1] = f2bf(v.y * ga + be);
        dst[2] = f2bf(v.z * ga + be);
        dst[3] = f2bf(v.w * ga + be);
    }
    __syncthreads();
    // r partials: r_j += sum_{cl} cvec[c0+cl] * h[cl][j]   (tile is resident in LDS)
    {
        int j = tid & 63, part = tid >> 6;
        float rs_ = 0.f;
#pragma unroll
        for (int q = 0; q < 16; ++q) {
            int cl = part * 16 + q;
            rs_ += cvec[c0 + cl] * bf2f(t[cl * TSTR + j]);
        }
        rp[part][j] = rs_;
    }
    __syncthreads();
    if (tid < 64) {
        float s = rp[0][tid] + rp[1][tid] + rp[2][tid] + rp[3][tid];
        atomicAdd(&rbuf[(size_t)b * NSPAT + n0 + tid], s);
    }
    u16* hb = hT + ((size_t)b * NSPAT + n0) * CDIM + c0;
#pragma unroll
    for (int p = 0; p < 4; ++p) {
        int nl = p * 16 + (tid >> 4);
        int cl4 = (tid & 15) << 2;
        ushort4 o;
        o.x = t[(cl4 + 0) * TSTR + nl];
        o.y = t[(cl4 + 1) * TSTR + nl];
        o.z = t[(cl4 + 2) * TSTR + nl];
        o.w = t[(cl4 + 3) * TSTR + nl];
        *(ushort4*)(hb + (size_t)nl * CDIM + cl4) = o;
    }
}

// ================= D3: gwv: [g; WV] = wmega . h  (+bpv on WV rows) ====================
// grid (BATCH, 4, 4), 512 thr: y = n-tile(256), z = m-tile(256) of [g(2); WV(2)].
// 256 blocks = exactly 1.0 round.
__global__ __launch_bounds__(512, 2) void qkv_kernel(
    const u16* __restrict__ wmega, const u16* __restrict__ hT,
    const float* __restrict__ bpv,
    u16* __restrict__ gT, u16* __restrict__ WV) {
    extern __shared__ u16 smem[];
    int z = blockIdx.x;
    int n0 = blockIdx.y << 8;
    int m0 = blockIdx.z << 8;
    const u16* Bb = hT + (size_t)z * CDIM * NSPAT;
    ACC_INIT84;
    gemm256x256(wmega, Bb, CDIM, CDIM, CDIM, m0, n0, smem, acc);
    int lane = threadIdx.x & 63, wave = threadIdx.x >> 6;
    int quad = lane >> 4, lrow = lane & 15;
    int wrow = wave >> 2, wcol = wave & 3;
    if (blockIdx.z < 2) {  // g rows: transposed packed store to gT[n][c], ldc=512, NO bias
        u16* gp = gT + (size_t)z * NSPAT * CDIM;
#pragma unroll
        for (int mf = 0; mf < 8; ++mf) {
            int R0 = m0 + wrow * 128 + mf * 16 + (quad << 2);
#pragma unroll
            for (int nf = 0; nf < 4; ++nf) {
                int Cc = n0 + wcol * 64 + nf * 16 + lrow;
                uint2 u;
                u.x = f2bf2(acc[mf][nf][0], acc[mf][nf][1]);
                u.y = f2bf2(acc[mf][nf][2], acc[mf][nf][3]);
                *(uint2*)&gp[(size_t)Cc * CDIM + R0] = u;
            }
        }
    } else {  // WV rows: natural store WV[o][n] + bpv
        u16* Wp = WV + (size_t)z * CDIM * NSPAT;
#pragma unroll
        for (int mf = 0; mf < 8; ++mf) {
            int R = m0 - 512 + wrow * 128 + mf * 16 + (quad << 2);
            float4 pv = *(const float4*)&bpv[R];
#pragma unroll
            for (int nf = 0; nf < 4; ++nf) {
                int Cc = n0 + wcol * 64 + nf * 16 + lrow;
                Wp[(size_t)(R + 0) * NSPAT + Cc] = f2bf(acc[mf][nf][0] + pv.x);
                Wp[(size_t)(R + 1) * NSPAT + Cc] = f2bf(acc[mf][nf][1] + pv.y);
                Wp[(size_t)(R + 2) * NSPAT + Cc] = f2bf(acc[mf][nf][2] + pv.z);
                Wp[(size_t)(R + 3) * NSPAT + Cc] = f2bf(acc[mf][nf][3] + pv.w);
            }
        }
    }
}

// ================= D4: scores: D[j][i] = g_j . h_i  (+ r_j), exp, row-sums ============
// grid (BATCH, 4, 4), 512 thr: y = i-tile(256), z = j-tile(256).
__global__ __launch_bounds__(512, 2) void scores_kernel(
    const u16* __restrict__ gT, const u16* __restrict__ hT,
    u16* __restrict__ P, float* __restrict__ lsums, const float* __restrict__ rbuf,
    float scale) {
    extern __shared__ u16 smem[];
    int z = blockIdx.x;
    int n0 = blockIdx.y << 8;                // i tile (N-dim)
    int m0 = blockIdx.z << 8;                // j tile (M-dim)
    const u16* gb = gT + (size_t)z * NSPAT * CDIM;
    const u16* hb = hT + (size_t)z * CDIM * NSPAT;
    ACC_INIT84;
    gemm256x256(gb, hb, CDIM, CDIM, CDIM, m0, n0, smem, acc);
    int lane = threadIdx.x & 63, wave = threadIdx.x >> 6;
    int quad = lane >> 4, lrow = lane & 15;
    int wrow = wave >> 2, wcol = wave & 3;
    u16* Pp = P + (size_t)z * NSPAT * NSPAT;
    float* ls = lsums + (size_t)z * NSPAT;
    const float* rb = rbuf + (size_t)z * NSPAT;
#pragma unroll
    for (int nf = 0; nf < 4; ++nf) {
        int Ci = n0 + wcol * 64 + nf * 16 + lrow;    // i (column of D)
        float part = 0.f;
#pragma unroll
        for (int mf = 0; mf < 8; ++mf) {
            int Rj0 = m0 + wrow * 128 + mf * 16 + (quad << 2);   // j rows, 4 consecutive
            float4 rv = *(const float4*)&rb[Rj0];
            float e0 = __expf((acc[mf][nf][0] + rv.x) * scale);
            float e1 = __expf((acc[mf][nf][1] + rv.y) * scale);
            float e2 = __expf((acc[mf][nf][2] + rv.z) * scale);
            float e3 = __expf((acc[mf][nf][3] + rv.w) * scale);
            part += (e0 + e1) + (e2 + e3);
            uint2 u;
            u.x = f2bf2(e0, e1);
            u.y = f2bf2(e2, e3);
            *(uint2*)&Pp[(size_t)Ci * NSPAT + Rj0] = u;
        }
        part += __shfl_xor(part, 16);
        part += __shfl_xor(part, 32);
        if (lane < 16) atomicAdd(&ls[Ci], part);
    }
}

// ================= D5: final (swapped operands): D[i][o] = P_i . WV_o =================
// grid (BATCH, 4, 4), 512 thr: y = o-tile(128), z = i-tile(256).
__global__ __launch_bounds__(512, 2) void final_kernel(
    const u16* __restrict__ WV, const u16* __restrict__ P, const float* __restrict__ lsums,
    const float* __restrict__ bias, const float* __restrict__ x, float* __restrict__ out) {
    extern __shared__ u16 smem[];
    int z = blockIdx.x;
    int n0 = blockIdx.y << 7;                // o tile (N-dim, 4 tiles of 128)
    int m0 = blockIdx.z << 8;                // i tile (M-dim, 4 tiles of 256)
    const u16* Pb = P + (size_t)z * NSPAT * NSPAT;
    const u16* WVb = WV + (size_t)z * CDIM * NSPAT;
    ACC_INIT44;
    gemm256x128(Pb, WVb, NSPAT, NSPAT, NSPAT, m0, n0, smem, acc);
    int lane = threadIdx.x & 63, wave = threadIdx.x >> 6;
    int quad = lane >> 4, lrow = lane & 15;
    int wrow = wave >> 1, wcol = wave & 1;
    float* Op = out + (size_t)z * CDIM * NSPAT;
    const float* xr = x + (size_t)z * CDIM * NSPAT;
    const float* li = lsums + (size_t)z * NSPAT;
#pragma unroll
    for (int mf = 0; mf < 4; ++mf) {
        int Ri0 = m0 + wrow * 64 + mf * 16 + (quad << 2);        // i, 4 consecutive
        float4 lv = *(const float4*)&li[Ri0];
        float s0 = __builtin_amdgcn_rcpf(lv.x);
        float s1 = __builtin_amdgcn_rcpf(lv.y);
        float s2 = __builtin_amdgcn_rcpf(lv.z);
        float s3 = __builtin_amdgcn_rcpf(lv.w);
#pragma unroll
        for (int nf = 0; nf < 4; ++nf) {
            int Co = n0 + wcol * 64 + nf * 16 + lrow;            // o
            float bv = bias[Co];
            size_t off = (size_t)Co * NSPAT + Ri0;
            float4 xv = *(const float4*)&xr[off];
            float4 o;
            o.x = acc[mf][nf][0] * s0 + bv + xv.x;
            o.y = acc[mf][nf][1] * s1 + bv + xv.y;
            o.z = acc[mf][nf][2] * s2 + bv + xv.z;
            o.w = acc[mf][nf][3] * s3 + bv + xv.w;
            *(float4*)&Op[off] = o;
        }
    }
}

// ================= launch =================
extern "C" void kernel_launch(void* const* d_in, const int* in_sizes, int n_in,
                              void* d_out, int out_size, void* d_ws, size_t ws_size,
                              hipStream_t stream) {
    const float* x      = (const float*)d_in[0];
    const float* gamma  = (const float*)d_in[1];
    const float* beta   = (const float*)d_in[2];
    const float* w_qkv  = (const float*)d_in[3];
    const float* b_qkv  = (const float*)d_in[4];
    const float* w_proj = (const float*)d_in[5];
    const float* b_proj = (const float*)d_in[6];
    float* out = (float*)d_out;

    const size_t CN = (size_t)CDIM * NSPAT;   // 524288
    const size_t NN = (size_t)NSPAT * NSPAT;  // 1048576
    const float SCALE = 0.044194173824159216f;
    const int LDS_BIG = 131072;   // 256x256 core
    const int LDS_MED = 98304;    // 256x128 core

    static bool lds_attr_done = false;
    if (!lds_attr_done) {
        hipFuncSetAttribute((const void*)qkv_kernel,
                            hipFuncAttributeMaxDynamicSharedMemorySize, LDS_BIG);
        hipFuncSetAttribute((const void*)scores_kernel,
                            hipFuncAttributeMaxDynamicSharedMemorySize, LDS_BIG);
        hipFuncSetAttribute((const void*)final_kernel,
                            hipFuncAttributeMaxDynamicSharedMemorySize, LDS_MED);
        lds_attr_done = true;
    }

    char* ws = (char*)d_ws;
    float* stats_part = (float*)ws;                           // 512x2 floats = 4 KB
    float* bpv     = (float*)(ws + 4096);                     // 2 KB
    float* cvec    = (float*)(ws + 6144);                     // 2 KB
    u16* wmega     = (u16*)(ws + 8192);                       // [M; Wpv] 1024x512 bf16 (1MB)
    u16* wproj_bf  = wmega + (size_t)1024 * CDIM;             // 0.5 MB
    u16* wq_t      = wproj_bf + (size_t)CDIM * CDIM;          // 0.5 MB
    u16* wk_t      = wq_t + (size_t)CDIM * CDIM;              // 0.5 MB
    u16* wv_t      = wk_t + (size_t)CDIM * CDIM;              // 0.5 MB
    u16* hT        = wv_t + (size_t)CDIM * CDIM;              // 16.8 MB [n][c]
    u16* gT        = hT + BATCH * CN;                         // 16.8 MB [n][c]
    u16* WV        = gT + BATCH * CN;                         // 16.8 MB [o][n]
    u16* P         = WV + BATCH * CN;                         // 33.5 MB [i][j] unnorm
    float* lsums   = (float*)(P + BATCH * NN);                // 64 KB
    float* rbuf    = lsums + (size_t)BATCH * NSPAT;           // 64 KB (contiguous after lsums)

    prep_kernel<<<1002, 256, 0, stream>>>(
        w_qkv, w_proj, b_qkv, x, wproj_bf, wq_t, wk_t, wv_t, stats_part, lsums, bpv, cvec);

    gn_wpv_kernel<<<dim3(16, 8, 17), 256, 0, stream>>>(
        x, gamma, beta, stats_part, hT, wproj_bf, wq_t, wk_t, wv_t, wmega, cvec, rbuf);

    qkv_kernel<<<dim3(BATCH, 4, 4), 512, LDS_BIG, stream>>>(
        wmega, hT, bpv, gT, WV);

    scores_kernel<<<dim3(BATCH, 4, 4), 512, LDS_BIG, stream>>>(
        gT, hT, P, lsums, rbuf, SCALE);

    final_kernel<<<dim3(BATCH, 4, 4), 512, LDS_MED, stream>>>(WV, P, lsums, b_proj, x, out);
}